// Round 1
// 345.196 us; speedup vs baseline: 1.5005x; 1.5005x over previous
//
#include <hip/hip_runtime.h>

#define BB 128
#define TT 1024
#define VV 192
#define NTHREADS 256
#define NWAVES 4
#define LN2 0.69314718055994530942f
#define WS_STRIDE 448   // per-batch: F[192], Bv[192], cF,cB,gF,gB,slF,slB

typedef int   intx8   __attribute__((ext_vector_type(8)));
typedef float floatx2 __attribute__((ext_vector_type(2)));
typedef float floatx4 __attribute__((ext_vector_type(4)));

__device__ __forceinline__ float bf8_to_f32(unsigned char h) {
    floatx2 v = __builtin_amdgcn_cvt_pk_f32_bf8((int)(unsigned int)h, false);
    return v.x;
}
__device__ __forceinline__ unsigned char f32_to_bf8(float f) {
    int pk = __builtin_amdgcn_cvt_pk_bf8_f32(f, f, 0, false);
    return (unsigned char)(pk & 0xff);
}
__device__ __forceinline__ unsigned char f32_to_fp8(float f) {
    int pk = __builtin_amdgcn_cvt_pk_fp8_f32(f, f, 0, false);
    return (unsigned char)(pk & 0xff);
}

// LDS-only barrier: does NOT drain vmcnt (global loads stay in flight)
#define LBAR() __asm__ volatile("s_waitcnt lgkmcnt(0)\n\ts_barrier" ::: "memory")

// Bidirectional scan: grid (BB, 2). dir=0: forward alpha, 512 steps (t=1..512,
// emission rows 0..512). dir=1: backward delta recursion delta_t = emit_t + beta_t,
// D_t = pe_t * (transT . D_{t+1}), init D_1023 = pe_1023*exp(end), 510 delta-steps
// down to D_513, then one plain matvec -> exp(beta_512). Meeting point:
// logZ = LN2*(cF+cB) + log(sum_i F[i]*Bv[i]).
__launch_bounds__(NTHREADS, 1)
__global__ void crf_half_kernel(const float* __restrict__ emissions,
                                const int* __restrict__ tags,
                                const int* __restrict__ mask,
                                const float* __restrict__ trans,
                                const float* __restrict__ start_trans,
                                const float* __restrict__ end_trans,
                                float* __restrict__ ws)
{
    const int b = blockIdx.x;
    const int dir = blockIdx.y;          // 0 = forward, 1 = backward
    const int tid = threadIdx.x;
    const int lane = tid & 63;
    const int wid = tid >> 6;        // 0..3
    const int quad = lane >> 4;      // 0..3
    const int col = lane & 15;       // 0..15

    __shared__ __align__(16) unsigned char qpad[2][256];
    __shared__ int smask[TT];
    __shared__ float wg[NWAVES];
    __shared__ float wsl[NWAVES];

    const float* em_b = emissions + (size_t)b * TT * VV;
    const int* mask_b = mask + b * TT;
    float* wsb = ws + (size_t)b * WS_STRIDE;

    const int nl = wid * 48 + (quad < 3 ? quad : 0) * 16 + col;

    // u -> emission row: fwd u, bwd 1023-u
    #define ROWOF(u) (dir ? (TT - 1 - (u)) : (u))

    // ---- E fragments, e4m3, MX 16x16x128 B-operand: 2 K-tiles x 3 N-tiles ----
    // fwd: out[n] = sum_k q[k]*exp(trans[k,n])  -> byte(k,n) = exp(trans[k*V+n])
    // bwd: out[i] = sum_j D[j]*exp(trans[i,j])  -> byte(k,n) = exp(trans[n*V+k])
    intx8 ef[6];
    #pragma unroll
    for (int kt = 0; kt < 2; ++kt) {
        #pragma unroll
        for (int h = 0; h < 3; ++h) {
            const int n = wid * 48 + h * 16 + col;
            intx8 v;
            #pragma unroll
            for (int w = 0; w < 8; ++w) {
                unsigned int word = 0;
                #pragma unroll
                for (int by = 0; by < 4; ++by) {
                    int k = kt * 128 + quad * 32 + w * 4 + by;
                    float x = (k < VV) ? __expf(trans[dir ? (k + n * VV) : (k * VV + n)]) : 0.f;
                    word |= (unsigned int)f32_to_fp8(x) << (8 * by);
                }
                v[w] = (int)word;
            }
            ef[kt * 3 + h] = v;
        }
    }

    // ---- zero both Q buffers (pad bytes 192..255 must stay 0 forever) ----
    for (int i = tid; i < 512; i += NTHREADS) ((unsigned char*)qpad)[i] = 0;

    // ---- preload mask into LDS ----
    for (int t = tid; t < TT; t += NTHREADS) smask[t] = mask_b[t];

    // ---- raw emission registers for this lane's column (exp applied lazily) ----
    float em0[8], em1[8];
    #pragma unroll
    for (int r = 0; r < 8; ++r) em0[r] = em_b[(size_t)ROWOF(r) * VV + nl];
    #pragma unroll
    for (int r = 0; r < 8; ++r) em1[r] = em_b[(size_t)ROWOF(8 + r) * VV + nl];
    // fwd final step u=512 uses pe row 512 (outside the refill window)
    float em_fin = em_b[(size_t)ROWOF(512) * VV + nl];

    // ---- init Q0 ----
    __syncthreads();   // zero-fill visible before Q0 write
    if (tid < VV) {
        float a0 = dir ? (end_trans[tid] + em_b[(size_t)(TT - 1) * VV + tid])
                       : (start_trans[tid] + em_b[tid]);
        qpad[0][tid] = f32_to_bf8(fminf(__expf(a0), 28672.f));
    }
    float carry2 = 0.f;
    int cur = 0;
    float peprev = __expf(em0[0]);   // pe of row ROWOF(0); only used by bwd masked path
    __syncthreads();

    // one step u: consumes qpad[cur]; emraw = raw em[ROWOF(u)][nl]
    auto dostep = [&](int u, float emraw) {
        const unsigned char* qc = qpad[cur];
        const uint4* qp = (const uint4*)qc;
        uint4 w0 = qp[quad * 2];
        uint4 w1 = qp[quad * 2 + 1];
        uint4 w2 = qp[8 + quad * 2];
        uint4 w3 = qp[8 + quad * 2 + 1];
        float q0 = bf8_to_f32(qc[0]);
        int mk = smask[dir ? (TT - u) : u];   // fwd: m_u ; bwd: m_{1024-u}
        unsigned char prevb = 0;
        if (!mk) prevb = qc[nl];          // uniform branch; skipped when mask=1

        intx8 A0 = (intx8){(int)w0.x, (int)w0.y, (int)w0.z, (int)w0.w,
                           (int)w1.x, (int)w1.y, (int)w1.z, (int)w1.w};
        intx8 A1 = (intx8){(int)w2.x, (int)w2.y, (int)w2.z, (int)w2.w,
                           (int)w3.x, (int)w3.y, (int)w3.z, (int)w3.w};

        floatx4 acc[3];
        #pragma unroll
        for (int h = 0; h < 3; ++h) acc[h] = (floatx4){0.f, 0.f, 0.f, 0.f};
        #pragma unroll
        for (int h = 0; h < 3; ++h)
            acc[h] = __builtin_amdgcn_mfma_scale_f32_16x16x128_f8f6f4(
                         A0, ef[h], acc[h], 1, 0, 0, 0x7f7f7f7f, 0, 0x7f7f7f7f);
        #pragma unroll
        for (int h = 0; h < 3; ++h)
            acc[h] = __builtin_amdgcn_mfma_scale_f32_16x16x128_f8f6f4(
                         A1, ef[3 + h], acc[h], 1, 0, 0, 0x7f7f7f7f, 0, 0x7f7f7f7f);

        float r = __builtin_amdgcn_rcpf(q0);
        carry2 += mk ? __log2f(q0) : 0.f;
        float pe = __expf(emraw);

        if (quad < 3) {
            float qn = fminf(acc[quad][0] * pe * r, 28672.f);
            unsigned char nb;
            if (mk) {
                nb = f32_to_bf8(qn);
            } else {
                // fwd masked: alpha unchanged -> keep byte.
                // bwd masked: D_t = pe_t * D_{t+1} / pe_{t+1}
                nb = dir ? f32_to_bf8(fminf(bf8_to_f32(prevb) * pe *
                                            __builtin_amdgcn_rcpf(peprev), 28672.f))
                         : prevb;
            }
            qpad[cur ^ 1][nl] = nb;
        }
        LBAR();
        cur ^= 1;
        peprev = pe;
    };

    // ---- main loop: u = 1..495 in 16-step bodies; raw-em double buffer ----
    for (int u0 = 0; u0 < 496; u0 += 16) {
        if (u0 > 0) dostep(u0 + 0, em0[0]);
        dostep(u0 + 1, em0[1]);
        dostep(u0 + 2, em0[2]);
        dostep(u0 + 3, em0[3]);
        dostep(u0 + 4, em0[4]);
        dostep(u0 + 5, em0[5]);
        dostep(u0 + 6, em0[6]);
        dostep(u0 + 7, em0[7]);
        // refill em0 <- u-rows [u0+16, u0+24); first use 9 steps away
        {
            #pragma unroll
            for (int r = 0; r < 8; ++r) {
                int rr = u0 + 16 + r;
                em0[r] = em_b[(size_t)ROWOF(rr) * VV + nl];
            }
        }
        dostep(u0 + 8,  em1[0]);
        dostep(u0 + 9,  em1[1]);
        dostep(u0 + 10, em1[2]);
        dostep(u0 + 11, em1[3]);
        dostep(u0 + 12, em1[4]);
        dostep(u0 + 13, em1[5]);
        dostep(u0 + 14, em1[6]);
        dostep(u0 + 15, em1[7]);
        // refill em1 <- u-rows [u0+24, u0+32)
        {
            #pragma unroll
            for (int r = 0; r < 8; ++r) {
                int rr = u0 + 24 + r;
                em1[r] = em_b[(size_t)ROWOF(rr) * VV + nl];
            }
        }
    }
    // ---- tail: u = 496..510 common ----
    dostep(496, em0[0]); dostep(497, em0[1]); dostep(498, em0[2]); dostep(499, em0[3]);
    dostep(500, em0[4]); dostep(501, em0[5]); dostep(502, em0[6]); dostep(503, em0[7]);
    dostep(504, em1[0]); dostep(505, em1[1]); dostep(506, em1[2]); dostep(507, em1[3]);
    dostep(508, em1[4]); dostep(509, em1[5]); dostep(510, em1[6]);

    if (dir == 0) {
        dostep(511, em1[7]);
        dostep(512, em_fin);
        // F[i] = exp(alpha_512[i]) / 2^cF   (bf8-quantized, same as before)
        if (tid < VV) wsb[tid] = bf8_to_f32(qpad[cur][tid]);
    } else {
        // final plain matvec (no pe, no renorm): exp(beta_512) from D_513, mask m_513
        const unsigned char* qc = qpad[cur];
        const uint4* qp = (const uint4*)qc;
        uint4 w0 = qp[quad * 2];
        uint4 w1 = qp[quad * 2 + 1];
        uint4 w2 = qp[8 + quad * 2];
        uint4 w3 = qp[8 + quad * 2 + 1];
        int mk = smask[513];
        intx8 A0 = (intx8){(int)w0.x, (int)w0.y, (int)w0.z, (int)w0.w,
                           (int)w1.x, (int)w1.y, (int)w1.z, (int)w1.w};
        intx8 A1 = (intx8){(int)w2.x, (int)w2.y, (int)w2.z, (int)w2.w,
                           (int)w3.x, (int)w3.y, (int)w3.z, (int)w3.w};
        floatx4 acc[3];
        #pragma unroll
        for (int h = 0; h < 3; ++h) acc[h] = (floatx4){0.f, 0.f, 0.f, 0.f};
        #pragma unroll
        for (int h = 0; h < 3; ++h)
            acc[h] = __builtin_amdgcn_mfma_scale_f32_16x16x128_f8f6f4(
                         A0, ef[h], acc[h], 1, 0, 0, 0x7f7f7f7f, 0, 0x7f7f7f7f);
        #pragma unroll
        for (int h = 0; h < 3; ++h)
            acc[h] = __builtin_amdgcn_mfma_scale_f32_16x16x128_f8f6f4(
                         A1, ef[3 + h], acc[h], 1, 0, 0, 0x7f7f7f7f, 0, 0x7f7f7f7f);
        if (quad < 3) {
            float v = acc[quad][0];
            if (!mk) v = bf8_to_f32(qc[nl]) * __builtin_amdgcn_rcpf(peprev); // beta_512=beta_513
            wsb[192 + nl] = v;
        }
    }
    if (tid == 0) wsb[384 + dir] = carry2;   // carry is lane-uniform

    // ---- gold score partials + seq_len partials (this half's t-range) ----
    float gp = 0.f;
    float sl = 0.f;
    for (int t = tid; t < TT; t += NTHREADS) {
        bool inS = dir ? (t >= 512) : (t < 512);
        if (inS) sl += (float)smask[t];
        bool inG = dir ? (t >= 513) : (t >= 1 && t <= 512);
        if (inG) {
            int tg  = tags[b * TT + t];
            int tgp = tags[b * TT + t - 1];
            float term = em_b[(size_t)t * VV + tg] + trans[tgp * VV + tg];
            gp += smask[t] ? term : 0.f;
        }
    }
    #pragma unroll
    for (int off = 1; off < 64; off <<= 1) {
        gp += __shfl_xor(gp, off);
        sl += __shfl_xor(sl, off);
    }
    if (lane == 0) { wg[wid] = gp; wsl[wid] = sl; }
    __syncthreads();
    if (tid == 0) {
        float g = 0.f, s = 0.f;
        for (int w = 0; w < NWAVES; ++w) { g += wg[w]; s += wsl[w]; }
        if (dir == 0) {
            int tg0 = tags[b * TT];
            g += start_trans[tg0] + em_b[tg0];
        }
        wsb[386 + dir] = g;
        wsb[388 + dir] = s;
    }
}

// tiny combine: logZ = LN2*(cF+cB) + log(dot(F,Bv)); loss = (logZ - gold)/seq_len
__global__ void crf_combine(const float* __restrict__ ws,
                            const int* __restrict__ tags,
                            const float* __restrict__ end_trans,
                            float* __restrict__ out)
{
    const int b = blockIdx.x;
    const int lane = threadIdx.x;   // 64 threads
    const float* wsb = ws + (size_t)b * WS_STRIDE;
    float s = 0.f;
    #pragma unroll
    for (int i = lane; i < VV; i += 64) s += wsb[i] * wsb[192 + i];
    #pragma unroll
    for (int off = 1; off < 64; off <<= 1) s += __shfl_xor(s, off);
    if (lane == 0) {
        float logden = LN2 * (wsb[384] + wsb[385]) + __logf(s + 1e-8f);
        float gold = wsb[386] + wsb[387];
        int seqs = (int)(wsb[388] + wsb[389]);
        int last_idx = seqs - 1; if (last_idx < 0) last_idx = 0;
        gold += end_trans[tags[b * TT + last_idx]];
        float seqf = fmaxf((float)seqs, 1.0f);
        out[b] = (logden - gold) / seqf;
    }
}

extern "C" void kernel_launch(void* const* d_in, const int* in_sizes, int n_in,
                              void* d_out, int out_size, void* d_ws, size_t ws_size,
                              hipStream_t stream) {
    const float* emissions   = (const float*)d_in[0];
    const int*   tags        = (const int*)d_in[1];
    const int*   mask        = (const int*)d_in[2];
    const float* trans       = (const float*)d_in[3];
    const float* start_trans = (const float*)d_in[4];
    const float* end_trans   = (const float*)d_in[5];
    float* out = (float*)d_out;
    float* ws  = (float*)d_ws;   // needs 128*448*4 = 229 KB

    crf_half_kernel<<<dim3(BB, 2), NTHREADS, 0, stream>>>(emissions, tags, mask, trans,
                                                          start_trans, end_trans, ws);
    crf_combine<<<BB, 64, 0, stream>>>(ws, tags, end_trans, out);
}

// Round 3
// 292.035 us; speedup vs baseline: 1.7737x; 1.1820x over previous
//
#include <hip/hip_runtime.h>

#define BB 128
#define TT 1024
#define VV 192
#define NTHREADS 256
#define NWAVES 4
#define LN2 0.69314718055994530942f
#define WS_STRIDE 448   // per-batch: F[192], Bv[192], cF,cB,gF,gB,slF,slB

typedef int   intx8   __attribute__((ext_vector_type(8)));
typedef float floatx2 __attribute__((ext_vector_type(2)));
typedef float floatx4 __attribute__((ext_vector_type(4)));

__device__ __forceinline__ float bf8_to_f32(unsigned char h) {
    floatx2 v = __builtin_amdgcn_cvt_pk_f32_bf8((int)(unsigned int)h, false);
    return v.x;
}
__device__ __forceinline__ unsigned char f32_to_bf8(float f) {
    int pk = __builtin_amdgcn_cvt_pk_bf8_f32(f, f, 0, false);
    return (unsigned char)(pk & 0xff);
}
__device__ __forceinline__ unsigned char f32_to_fp8(float f) {
    int pk = __builtin_amdgcn_cvt_pk_fp8_f32(f, f, 0, false);
    return (unsigned char)(pk & 0xff);
}

// LDS-only barrier: does NOT drain vmcnt (global loads stay in flight)
#define LBAR() __asm__ volatile("s_waitcnt lgkmcnt(0)\n\ts_barrier" ::: "memory")

// DIR=0: forward alpha, 512 steps (t=1..512, emission rows 0..512).
// DIR=1: backward delta recursion delta_t = emit_t + beta_t:
//   D_t = pe_t * (transT . D_{t+1}), init D_1023 = pe_1023*exp(end),
//   510 delta-steps down to D_513, then one plain matvec -> exp(beta_512).
// Meeting point: logZ = LN2*(cF+cB) + log(sum_i F[i]*Bv[i]).
template<int DIR>
__device__ __forceinline__ void crf_body(const float* __restrict__ emissions,
                                         const int* __restrict__ tags,
                                         const int* __restrict__ mask,
                                         const float* __restrict__ trans,
                                         const float* __restrict__ start_trans,
                                         const float* __restrict__ end_trans,
                                         float* __restrict__ ws)
{
    const int b = blockIdx.x;
    const int tid = threadIdx.x;
    const int lane = tid & 63;
    const int wid = tid >> 6;        // 0..3
    const int quad = lane >> 4;      // 0..3
    const int col = lane & 15;       // 0..15

    __shared__ __align__(16) unsigned char qpad[2][256];
    __shared__ unsigned int smaskp[33];   // packed mask bits, word 32 = 0 pad
    __shared__ float wg[NWAVES];
    __shared__ float wsl[NWAVES];

    const float* em_b = emissions + (size_t)b * TT * VV;
    const int* mask_b = mask + b * TT;
    float* wsb = ws + (size_t)b * WS_STRIDE;

    // quads 0..2 own one column; quad 3 duplicates quad 0 (writes identical byte)
    const int nl = wid * 48 + (quad < 3 ? quad : 0) * 16 + col;

    #define ROWOF(u) (DIR ? (TT - 1 - (u)) : (u))

    // ---- E fragments, e4m3, MX 16x16x128 B-operand: 2 K-tiles x 3 N-tiles ----
    // fwd: out[n] = sum_k q[k]*exp(trans[k,n])  -> byte(k,n) = exp(trans[k*V+n])
    // bwd: out[i] = sum_j D[j]*exp(trans[i,j])  -> byte(k,n) = exp(trans[n*V+k])
    intx8 ef[6];
    #pragma unroll
    for (int kt = 0; kt < 2; ++kt) {
        #pragma unroll
        for (int h = 0; h < 3; ++h) {
            const int n = wid * 48 + h * 16 + col;
            intx8 v;
            #pragma unroll
            for (int w = 0; w < 8; ++w) {
                unsigned int word = 0;
                #pragma unroll
                for (int by = 0; by < 4; ++by) {
                    int k = kt * 128 + quad * 32 + w * 4 + by;
                    float x = (k < VV) ? __expf(trans[DIR ? (k + n * VV) : (k * VV + n)]) : 0.f;
                    word |= (unsigned int)f32_to_fp8(x) << (8 * by);
                }
                v[w] = (int)word;
            }
            ef[kt * 3 + h] = v;
        }
    }

    // ---- zero both Q buffers (pad bytes 192..255 must stay 0 forever) ----
    for (int i = tid; i < 512; i += NTHREADS) ((unsigned char*)qpad)[i] = 0;

    // ---- build packed mask bits ----
    if (tid < 33) {
        if (tid == 32) smaskp[32] = 0u;
        else {
            unsigned int m = 0;
            #pragma unroll 4
            for (int j = 0; j < 32; ++j) m |= (mask_b[tid * 32 + j] ? 1u : 0u) << j;
            smaskp[tid] = m;
        }
    }

    // ---- raw emission registers for this lane's column (exp applied lazily) ----
    float em0[8], em1[8];
    #pragma unroll
    for (int r = 0; r < 8; ++r) em0[r] = em_b[(size_t)ROWOF(r) * VV + nl];
    #pragma unroll
    for (int r = 0; r < 8; ++r) em1[r] = em_b[(size_t)ROWOF(8 + r) * VV + nl];
    // fwd final step u=512 uses pe row 512 (outside the refill window)
    float em_fin = em_b[(size_t)ROWOF(512) * VV + nl];

    // ---- init Q0 ----
    __syncthreads();   // zero-fill + smaskp visible
    if (tid < VV) {
        float a0 = DIR ? (end_trans[tid] + em_b[(size_t)(TT - 1) * VV + tid])
                       : (start_trans[tid] + em_b[tid]);
        qpad[0][tid] = f32_to_bf8(fminf(__expf(a0), 28672.f));
    }
    float carry2 = 0.f;
    int cur = 0;
    float peprev = __expf(em0[0]);   // pe of row ROWOF(0); only used by bwd masked path
    __syncthreads();

    // per-16-step-window scalar mask fetch
    unsigned long long mk64 = 0; int boff = 0;
    auto fetchwin = [&](int u0w) {
        int wbase = DIR ? (TT - u0w - 16) : u0w;
        int mw = wbase >> 5;
        unsigned mlo = (unsigned)__builtin_amdgcn_readfirstlane((int)smaskp[mw]);
        unsigned mhi = (unsigned)__builtin_amdgcn_readfirstlane((int)smaskp[mw + 1]);
        mk64 = (((unsigned long long)mhi) << 32) | (unsigned long long)mlo;
        boff = wbase & 31;
    };
    auto getmk = [&](int i) -> int {
        int sh = DIR ? (boff + 16 - i) : (boff + i);
        return (int)((mk64 >> sh) & 1ull);
    };

    // one CRF step: consumes qpad[cur]; emraw = raw em[row][nl]; mk = mask bit
    auto dostep = [&](float emraw, int mk) {
        unsigned char* qc = qpad[cur];
        const intx8* qv = (const intx8*)qc;
        intx8 A0 = qv[quad];        // state bytes [quad*32, quad*32+32)
        intx8 A1 = qv[quad + 4];    // state bytes [128+quad*32, ...)
        unsigned char prevb = 0;
        if (!mk) prevb = qc[nl];    // uniform branch; skipped when mask=1

        floatx4 aA[3], aB[3];
        #pragma unroll
        for (int h = 0; h < 3; ++h) { aA[h] = (floatx4){0.f,0.f,0.f,0.f};
                                      aB[h] = (floatx4){0.f,0.f,0.f,0.f}; }
        #pragma unroll
        for (int h = 0; h < 3; ++h)
            aA[h] = __builtin_amdgcn_mfma_scale_f32_16x16x128_f8f6f4(
                        A0, ef[h], aA[h], 1, 0, 0, 0x7f7f7f7f, 0, 0x7f7f7f7f);
        #pragma unroll
        for (int h = 0; h < 3; ++h)
            aB[h] = __builtin_amdgcn_mfma_scale_f32_16x16x128_f8f6f4(
                        A1, ef[3 + h], aB[h], 1, 0, 0, 0x7f7f7f7f, 0, 0x7f7f7f7f);

        int q0i = __builtin_amdgcn_readfirstlane(A0[0]);   // state byte 0 (lane0=quad0)
        float q0 = bf8_to_f32((unsigned char)(q0i & 0xff));
        float r = __builtin_amdgcn_rcpf(q0);
        carry2 += mk ? __log2f(q0) : 0.f;
        float pe = __expf(emraw);
        float sc = pe * r;

        float s0 = aA[0][0] + aB[0][0];
        float s1 = aA[1][0] + aB[1][0];
        float s2 = aA[2][0] + aB[2][0];
        float v = (quad == 1) ? s1 : ((quad == 2) ? s2 : s0);  // quad3 -> s0 (dup of quad0)
        float qn = fminf(v * sc, 28672.f);
        unsigned char nb;
        if (mk) {
            nb = f32_to_bf8(qn);
        } else {
            // fwd masked: alpha unchanged -> keep byte.
            // bwd masked: D_t = pe_t * D_{t+1} / pe_{t+1}
            nb = DIR ? f32_to_bf8(fminf(bf8_to_f32(prevb) * pe *
                                        __builtin_amdgcn_rcpf(peprev), 28672.f))
                     : prevb;
        }
        qpad[cur ^ 1][nl] = nb;     // unconditional; quad3 writes identical duplicate
        LBAR();
        cur ^= 1;
        if (DIR) peprev = pe;
    };

    // ---- main loop: u = 1..495 in 16-step bodies; raw-em double buffer ----
    for (int u0 = 0; u0 < 496; u0 += 16) {
        fetchwin(u0);
        if (u0 > 0) dostep(em0[0], getmk(0));
        dostep(em0[1], getmk(1));
        dostep(em0[2], getmk(2));
        dostep(em0[3], getmk(3));
        dostep(em0[4], getmk(4));
        dostep(em0[5], getmk(5));
        dostep(em0[6], getmk(6));
        dostep(em0[7], getmk(7));
        // refill em0 <- u-rows [u0+16, u0+24); first use 9 steps away
        {
            #pragma unroll
            for (int r = 0; r < 8; ++r) {
                int rr = u0 + 16 + r;
                em0[r] = em_b[(size_t)ROWOF(rr) * VV + nl];
            }
        }
        dostep(em1[0], getmk(8));
        dostep(em1[1], getmk(9));
        dostep(em1[2], getmk(10));
        dostep(em1[3], getmk(11));
        dostep(em1[4], getmk(12));
        dostep(em1[5], getmk(13));
        dostep(em1[6], getmk(14));
        dostep(em1[7], getmk(15));
        // refill em1 <- u-rows [u0+24, u0+32)
        {
            #pragma unroll
            for (int r = 0; r < 8; ++r) {
                int rr = u0 + 24 + r;
                em1[r] = em_b[(size_t)ROWOF(rr) * VV + nl];
            }
        }
    }
    // ---- tail: u = 496..510 common ----
    fetchwin(496);
    dostep(em0[0], getmk(0)); dostep(em0[1], getmk(1));
    dostep(em0[2], getmk(2)); dostep(em0[3], getmk(3));
    dostep(em0[4], getmk(4)); dostep(em0[5], getmk(5));
    dostep(em0[6], getmk(6)); dostep(em0[7], getmk(7));
    dostep(em1[0], getmk(8)); dostep(em1[1], getmk(9));
    dostep(em1[2], getmk(10)); dostep(em1[3], getmk(11));
    dostep(em1[4], getmk(12)); dostep(em1[5], getmk(13));
    dostep(em1[6], getmk(14));

    if (DIR == 0) {
        dostep(em1[7], getmk(15));   // u=511
        dostep(em_fin, getmk(16));   // u=512 (shift boff+16 -> mask[512])
        // F[i] = exp(alpha_512[i]) / 2^cF   (bf8-quantized)
        if (tid < VV) wsb[tid] = bf8_to_f32(qpad[cur][tid]);
    } else {
        // final plain matvec (no pe, no renorm): exp(beta_512) from D_513, mask m_513
        unsigned char* qc = qpad[cur];
        const intx8* qv = (const intx8*)qc;
        intx8 A0 = qv[quad];
        intx8 A1 = qv[quad + 4];
        int mk = (int)((smaskp[513 >> 5] >> (513 & 31)) & 1u);
        floatx4 aA[3], aB[3];
        #pragma unroll
        for (int h = 0; h < 3; ++h) { aA[h] = (floatx4){0.f,0.f,0.f,0.f};
                                      aB[h] = (floatx4){0.f,0.f,0.f,0.f}; }
        #pragma unroll
        for (int h = 0; h < 3; ++h)
            aA[h] = __builtin_amdgcn_mfma_scale_f32_16x16x128_f8f6f4(
                        A0, ef[h], aA[h], 1, 0, 0, 0x7f7f7f7f, 0, 0x7f7f7f7f);
        #pragma unroll
        for (int h = 0; h < 3; ++h)
            aB[h] = __builtin_amdgcn_mfma_scale_f32_16x16x128_f8f6f4(
                        A1, ef[3 + h], aB[h], 1, 0, 0, 0x7f7f7f7f, 0, 0x7f7f7f7f);
        if (quad < 3) {
            float s0 = aA[0][0] + aB[0][0];
            float s1 = aA[1][0] + aB[1][0];
            float s2 = aA[2][0] + aB[2][0];
            float v = (quad == 1) ? s1 : ((quad == 2) ? s2 : s0);
            if (!mk) v = bf8_to_f32(qc[nl]) * __builtin_amdgcn_rcpf(peprev); // beta_512=beta_513
            wsb[192 + nl] = v;
        }
    }
    if (tid == 0) wsb[384 + DIR] = carry2;   // carry is lane-uniform

    // ---- gold score partials + seq_len partials (this half's t-range) ----
    float gp = 0.f;
    float sl = 0.f;
    for (int t = tid; t < TT; t += NTHREADS) {
        int mk = (int)((smaskp[t >> 5] >> (t & 31)) & 1u);
        bool inS = DIR ? (t >= 512) : (t < 512);
        if (inS) sl += (float)mk;
        bool inG = DIR ? (t >= 513) : (t >= 1 && t <= 512);
        if (inG) {
            int tg  = tags[b * TT + t];
            int tgp = tags[b * TT + t - 1];
            float term = em_b[(size_t)t * VV + tg] + trans[tgp * VV + tg];
            gp += mk ? term : 0.f;
        }
    }
    #pragma unroll
    for (int off = 1; off < 64; off <<= 1) {
        gp += __shfl_xor(gp, off);
        sl += __shfl_xor(sl, off);
    }
    if (lane == 0) { wg[wid] = gp; wsl[wid] = sl; }
    __syncthreads();
    if (tid == 0) {
        float g = 0.f, s = 0.f;
        for (int w = 0; w < NWAVES; ++w) { g += wg[w]; s += wsl[w]; }
        if (DIR == 0) {
            int tg0 = tags[b * TT];
            g += start_trans[tg0] + em_b[tg0];
        }
        wsb[386 + DIR] = g;
        wsb[388 + DIR] = s;
    }
    #undef ROWOF
}

__launch_bounds__(NTHREADS, 1)
__global__ void crf_half_kernel(const float* __restrict__ emissions,
                                const int* __restrict__ tags,
                                const int* __restrict__ mask,
                                const float* __restrict__ trans,
                                const float* __restrict__ start_trans,
                                const float* __restrict__ end_trans,
                                float* __restrict__ ws)
{
    if (blockIdx.y == 0)
        crf_body<0>(emissions, tags, mask, trans, start_trans, end_trans, ws);
    else
        crf_body<1>(emissions, tags, mask, trans, start_trans, end_trans, ws);
}

// tiny combine: logZ = LN2*(cF+cB) + log(dot(F,Bv)); loss = (logZ - gold)/seq_len
__global__ void crf_combine(const float* __restrict__ ws,
                            const int* __restrict__ tags,
                            const float* __restrict__ end_trans,
                            float* __restrict__ out)
{
    const int b = blockIdx.x;
    const int lane = threadIdx.x;   // 64 threads
    const float* wsb = ws + (size_t)b * WS_STRIDE;
    float s = 0.f;
    #pragma unroll
    for (int i = lane; i < VV; i += 64) s += wsb[i] * wsb[192 + i];
    #pragma unroll
    for (int off = 1; off < 64; off <<= 1) s += __shfl_xor(s, off);
    if (lane == 0) {
        float logden = LN2 * (wsb[384] + wsb[385]) + __logf(s + 1e-8f);
        float gold = wsb[386] + wsb[387];
        int seqs = (int)(wsb[388] + wsb[389]);
        int last_idx = seqs - 1; if (last_idx < 0) last_idx = 0;
        gold += end_trans[tags[b * TT + last_idx]];
        float seqf = fmaxf((float)seqs, 1.0f);
        out[b] = (logden - gold) / seqf;
    }
}

extern "C" void kernel_launch(void* const* d_in, const int* in_sizes, int n_in,
                              void* d_out, int out_size, void* d_ws, size_t ws_size,
                              hipStream_t stream) {
    const float* emissions   = (const float*)d_in[0];
    const int*   tags        = (const int*)d_in[1];
    const int*   mask        = (const int*)d_in[2];
    const float* trans       = (const float*)d_in[3];
    const float* start_trans = (const float*)d_in[4];
    const float* end_trans   = (const float*)d_in[5];
    float* out = (float*)d_out;
    float* ws  = (float*)d_ws;   // needs 128*448*4 = 229 KB

    crf_half_kernel<<<dim3(BB, 2), NTHREADS, 0, stream>>>(emissions, tags, mask, trans,
                                                          start_trans, end_trans, ws);
    crf_combine<<<BB, 64, 0, stream>>>(ws, tags, end_trans, out);
}